// Round 2
// baseline (1438.828 us; speedup 1.0000x reference)
//
#include <hip/hip_runtime.h>
#include <hip/hip_bf16.h>

// Dilate (zero-insertion 2x2 upsample):
//   in : float32 (16, 64, 256, 256)  = 16,777,216 float4
//   out: float32 (16, 64, 512, 512)  = 67,108,864 float4
// out[b,c,2i,2j] = x[b,c,i,j]; all other outputs 0.
//
// Each thread: 1x 16B load from input row `r`, column-group w4 (4 floats),
// then writes:
//   even out row (2r):   2x 16B = [x0,0,x1,0],[x2,0,x3,0] at col 8*w4
//   odd  out row (2r+1): 2x 16B zeros at col 8*w4
// Per-lane 32B contiguous per row; wave covers contiguous 2KiB spans.
//
// Use native clang vector type: __builtin_nontemporal_* rejects HIP's
// struct-based float4 (compile error in round 1).

typedef float f32x4 __attribute__((ext_vector_type(4)));

#define W4_IN   64    // 256 / 4 float4 per input row
#define W4_OUT  128   // 512 / 4 float4 per output row

__global__ __launch_bounds__(256) void dilate_kernel(
    const f32x4* __restrict__ x, f32x4* __restrict__ out, int n4_in)
{
    const f32x4 z = (f32x4){0.f, 0.f, 0.f, 0.f};
    int stride = gridDim.x * blockDim.x;
    for (int g = blockIdx.x * blockDim.x + threadIdx.x; g < n4_in; g += stride) {
        int w4  = g & (W4_IN - 1);   // column group within input row
        int row = g >> 6;            // flattened (b*c*h) input row index

        f32x4 v = __builtin_nontemporal_load(&x[g]);

        f32x4 e0 = (f32x4){v.x, 0.f, v.y, 0.f};
        f32x4 e1 = (f32x4){v.z, 0.f, v.w, 0.f};

        // even output row = 2*row; base in float4 units
        long ebase = (long)row * (2L * W4_OUT) + (long)w4 * 2;
        __builtin_nontemporal_store(e0, &out[ebase]);
        __builtin_nontemporal_store(e1, &out[ebase + 1]);

        // odd output row = 2*row + 1: all zeros
        long obase = ebase + W4_OUT;
        __builtin_nontemporal_store(z, &out[obase]);
        __builtin_nontemporal_store(z, &out[obase + 1]);
    }
}

extern "C" void kernel_launch(void* const* d_in, const int* in_sizes, int n_in,
                              void* d_out, int out_size, void* d_ws, size_t ws_size,
                              hipStream_t stream) {
    const f32x4* x = (const f32x4*)d_in[0];
    f32x4* out = (f32x4*)d_out;

    int n4_in = in_sizes[0] / 4;   // 16*64*256*256 / 4 = 16,777,216

    int block = 256;
    int grid  = 2048;              // grid-stride; ~8 blocks/CU worth of waves
    dilate_kernel<<<grid, block, 0, stream>>>(x, out, n4_in);
}